// Round 9
// baseline (26.364 us; speedup 1.0000x reference)
//
#include <hip/hip_runtime.h>
#include <cmath>

#define NROWS 131072
#define TPB 256

// ---------------------------------------------------------------------------
// Sparse sub-tree evaluation (R8) + coalesced streaming reads (R9).
// Only 2 layer-1 modules are observable through the one-hot output routing;
// they consume 4 layer-0 modules, which consume 8 x-columns. All indices are
// grid-uniform. Instead of 8 scattered-per-lane gathers (stride-256B, ~3.5
// TB/s effective), each wave streams its 64 rows with one coalesced 256B
// load per row and distributes the 8 routed features to the owning lane via
// v_readlane (uniform SGPR index) + cndmask.
// ---------------------------------------------------------------------------

__device__ __forceinline__ float rl(float v, int sl) {
    return __int_as_float(__builtin_amdgcn_readlane(__float_as_int(v), sl));
}

// top-2 of v across 64 lanes; lowest-index tie-break matches jax.lax.top_k
__device__ __forceinline__ void wave_top2(float v, int lane, int& i1, int& i2) {
    float m1 = v;
#pragma unroll
    for (int off = 32; off; off >>= 1) m1 = fmaxf(m1, __shfl_xor(m1, off));
    unsigned long long bm = __ballot(v == m1);
    i1 = __ffsll(bm) - 1;
    float vx = (lane == i1) ? -INFINITY : v;
    float m2 = vx;
#pragma unroll
    for (int off = 32; off; off >>= 1) m2 = fmaxf(m2, __shfl_xor(m2, off));
    bm = __ballot(vx == m2);
    i2 = __ffsll(bm) - 1;
}

__global__ __launch_bounds__(TPB) void moe_sparse(
    const float* __restrict__ x,
    const float* __restrict__ emb0, const float* __restrict__ emb1,
    const float* __restrict__ emb_out,
    const float* __restrict__ W1_0, const float* __restrict__ b1_0,
    const float* __restrict__ W2_0, const float* __restrict__ b2_0,
    const float* __restrict__ W1_1, const float* __restrict__ b1_1,
    const float* __restrict__ W2_1, const float* __restrict__ b2_1,
    float* __restrict__ out) {

    // rt[0]=io1 rt[1]=io2 ; rt[2..5] = 4 active layer-0 modules ;
    // rt[6+2k], rt[7+2k] = x-columns (top1, top2) for layer-0 module k
    __shared__ int rt[14];

    if (threadIdx.x < 64) {
        const int lane = threadIdx.x;
        int io1, io2;
        wave_top2(emb_out[lane], lane, io1, io2);
        int a1, b1i, a2, b2i;
        wave_top2(emb1[lane * 64 + io1], lane, a1, b1i);
        wave_top2(emb1[lane * 64 + io2], lane, a2, b2i);
        const int mk[4] = {a1, b1i, a2, b2i};
        if (lane == 0) {
            rt[0] = io1; rt[1] = io2;
            rt[2] = a1; rt[3] = b1i; rt[4] = a2; rt[5] = b2i;
        }
#pragma unroll
        for (int k = 0; k < 4; ++k) {
            int c1, c2;
            wave_top2(emb0[lane * 64 + mk[k]], lane, c1, c2);
            if (lane == 0) { rt[6 + 2 * k] = c1; rt[7 + 2 * k] = c2; }
        }
    }
    __syncthreads();

    // broadcast routing into SGPRs
    const int io1 = __builtin_amdgcn_readfirstlane(rt[0]);
    const int io2 = __builtin_amdgcn_readfirstlane(rt[1]);
    int m[4], ca[4], cb[4];
#pragma unroll
    for (int k = 0; k < 4; ++k) {
        m[k]  = __builtin_amdgcn_readfirstlane(rt[2 + k]);
        ca[k] = __builtin_amdgcn_readfirstlane(rt[6 + 2 * k]);
        cb[k] = __builtin_amdgcn_readfirstlane(rt[7 + 2 * k]);
    }

    const int lane = threadIdx.x & 63;
    const int wave = blockIdx.x * (TPB / 64) + (threadIdx.x >> 6);
    const int row0 = wave * 64;           // this wave's 64 rows

    // ---- coalesced streaming: one 256B load per row; readlane-distribute ----
    float va[4] = {0, 0, 0, 0}, vb[4] = {0, 0, 0, 0};
    float vbuf[8];
#pragma unroll
    for (int i = 0; i < 8; ++i)
        vbuf[i] = x[(size_t)(row0 + i) * 64 + lane];

#pragma unroll
    for (int b = 0; b < 8; ++b) {
        float vnxt[8];
        if (b < 7) {
#pragma unroll
            for (int i = 0; i < 8; ++i)
                vnxt[i] = x[(size_t)(row0 + (b + 1) * 8 + i) * 64 + lane];
        }
#pragma unroll
        for (int i = 0; i < 8; ++i) {
            const int r = b * 8 + i;
            const bool own = (lane == r);
#pragma unroll
            for (int k = 0; k < 4; ++k) {
                const float sa = rl(vbuf[i], ca[k]);
                const float sb = rl(vbuf[i], cb[k]);
                va[k] = own ? sa : va[k];
                vb[k] = own ? sb : vb[k];
            }
        }
        if (b < 7) {
#pragma unroll
            for (int i = 0; i < 8; ++i) vbuf[i] = vnxt[i];
        }
    }
    // now each lane holds the 8 routed features of row (row0 + lane)

    // ---- layer 0: 4 active modules, f32, scalar weights ----
    float y[4];
#pragma unroll
    for (int k = 0; k < 4; ++k) {
        const float* w1 = W1_0 + m[k] * 24;
        const float* bb = b1_0 + m[k] * 12;
        const float* w2 = W2_0 + m[k] * 12;
        float acc = b2_0[m[k]];
#pragma unroll
        for (int j = 0; j < 12; ++j) {
            float h = fmaf(va[k], w1[j], fmaf(vb[k], w1[12 + j], bb[j]));
            acc = fmaf(fmaxf(h, 0.0f), w2[j], acc);
        }
        y[k] = acc;
    }

    // ---- layer 1: io1 consumes (y[0],y[1]); io2 consumes (y[2],y[3]) ----
    float z[2];
    const int mo[2] = {io1, io2};
#pragma unroll
    for (int k = 0; k < 2; ++k) {
        const float* w1 = W1_1 + mo[k] * 24;
        const float* bb = b1_1 + mo[k] * 12;
        const float* w2 = W2_1 + mo[k] * 12;
        const float g1 = k ? y[2] : y[0];
        const float g2 = k ? y[3] : y[1];
        float acc = b2_1[mo[k]];
#pragma unroll
        for (int j = 0; j < 12; ++j) {
            float h = fmaf(g1, w1[j], fmaf(g2, w1[12 + j], bb[j]));
            acc = fmaf(fmaxf(h, 0.0f), w2[j], acc);
        }
        z[k] = acc;
    }

    float2 res;
    res.x = 1.0f / (1.0f + __expf(-z[0]));
    res.y = 1.0f / (1.0f + __expf(-z[1]));
    reinterpret_cast<float2*>(out)[row0 + lane] = res;   // coalesced
}

extern "C" void kernel_launch(void* const* d_in, const int* in_sizes, int n_in,
                              void* d_out, int out_size, void* d_ws, size_t ws_size,
                              hipStream_t stream) {
    const float* x       = (const float*)d_in[0];
    // d_in[1] = task_id; NUM_TASKS == 1 so always 0.
    const float* emb0    = (const float*)d_in[2];
    const float* emb1    = (const float*)d_in[3];
    const float* emb_out = (const float*)d_in[4];
    const float* W1_0    = (const float*)d_in[5];
    const float* b1_0    = (const float*)d_in[6];
    const float* W2_0    = (const float*)d_in[7];
    const float* b2_0    = (const float*)d_in[8];
    const float* W1_1    = (const float*)d_in[9];
    const float* b1_1    = (const float*)d_in[10];
    const float* W2_1    = (const float*)d_in[11];
    const float* b2_1    = (const float*)d_in[12];

    moe_sparse<<<NROWS / TPB, TPB, 0, stream>>>(
        x, emb0, emb1, emb_out,
        W1_0, b1_0, W2_0, b2_0, W1_1, b1_1, W2_1, b2_1,
        (float*)d_out);
}

// Round 10
// 14.283 us; speedup vs baseline: 1.8458x; 1.8458x over previous
//
#include <hip/hip_runtime.h>
#include <cmath>

#define NROWS 131072
#define TPB 256

// ---------------------------------------------------------------------------
// Sparse sub-tree (R8, exact f32) + coalesced streaming + LDS distribution.
// Only 2 layer-1 modules are observable; they consume 4 layer-0 modules,
// which consume 8 x-columns (grid-uniform, data-independent of x).
// R8 gathered 8 scattered columns/row: ~2.1 TB/s effective (64 distinct
// 64B lines per load instruction). R9's readlane-distribute fixed BW but
// cost 16 VALU/row. Here: block streams its 256 rows fully coalesced
// (1KB/instruction), and routed elements are deposited to buf[row][slot]
// by ONE predicated ds_write per element-batch lane (8 active lanes/wave);
// reader side is 8 conflict-free ds_reads (stride-9 pad). ~2 LDS ops/row.
// Duplicate routed columns are deduped (first-occurrence map src[]).
// ---------------------------------------------------------------------------

// top-2 of v across 64 lanes; lowest-index tie-break matches jax.lax.top_k
__device__ __forceinline__ void wave_top2(float v, int lane, int& i1, int& i2) {
    float m1 = v;
#pragma unroll
    for (int off = 32; off; off >>= 1) m1 = fmaxf(m1, __shfl_xor(m1, off));
    unsigned long long bm = __ballot(v == m1);
    i1 = __ffsll(bm) - 1;
    float vx = (lane == i1) ? -INFINITY : v;
    float m2 = vx;
#pragma unroll
    for (int off = 32; off; off >>= 1) m2 = fmaxf(m2, __shfl_xor(m2, off));
    bm = __ballot(vx == m2);
    i2 = __ffsll(bm) - 1;
}

__global__ __launch_bounds__(TPB) void moe_sparse(
    const float* __restrict__ x,
    const float* __restrict__ emb0, const float* __restrict__ emb1,
    const float* __restrict__ emb_out,
    const float* __restrict__ W1_0, const float* __restrict__ b1_0,
    const float* __restrict__ W2_0, const float* __restrict__ b2_0,
    const float* __restrict__ W1_1, const float* __restrict__ b1_1,
    const float* __restrict__ W2_1, const float* __restrict__ b2_1,
    float* __restrict__ out) {

    // rt[0]=io1 rt[1]=io2 rt[2..5]=active layer-0 modules
    // rt[6..13]=ucol[8] (-1 = duplicate, no writer)  rt[14..21]=src[8]
    __shared__ int rt[22];
    __shared__ float buf[256 * 9];   // 9216 B, stride-9 pad (conflict-free)

    // ---- routing preamble on wave 0 ----
    if (threadIdx.x < 64) {
        const int lane = threadIdx.x;
        int io1, io2;
        wave_top2(emb_out[lane], lane, io1, io2);
        int a1, b1i, a2, b2i;
        wave_top2(emb1[lane * 64 + io1], lane, a1, b1i);
        wave_top2(emb1[lane * 64 + io2], lane, a2, b2i);
        const int mk[4] = {a1, b1i, a2, b2i};
        int cols[8];
#pragma unroll
        for (int k = 0; k < 4; ++k) {
            int c1, c2;
            wave_top2(emb0[lane * 64 + mk[k]], lane, c1, c2);
            cols[2 * k] = c1; cols[2 * k + 1] = c2;
        }
        // first-occurrence dedupe (all lanes compute; values uniform)
        int src[8];
#pragma unroll
        for (int s = 0; s < 8; ++s) {
            src[s] = s;
#pragma unroll
            for (int u = 0; u < 8; ++u) {
                if (u < s && cols[s] == cols[u] && src[s] == s) src[s] = u;
            }
        }
        if (lane == 0) {
            rt[0] = io1; rt[1] = io2;
            rt[2] = a1; rt[3] = b1i; rt[4] = a2; rt[5] = b2i;
#pragma unroll
            for (int s = 0; s < 8; ++s) {
                rt[6 + s]  = (src[s] == s) ? cols[s] : -1;  // ucol (writer map)
                rt[14 + s] = src[s];                        // reader map
            }
        }
    }
    __syncthreads();

    const int t = threadIdx.x;
    const int col = t & 63;

    // writer slot for this thread's column (-1 if not routed / duplicate)
    int slot = -1;
#pragma unroll
    for (int s = 0; s < 8; ++s) slot = (col == rt[6 + s]) ? s : slot;

    // uniform routing into SGPRs
    const int io1 = __builtin_amdgcn_readfirstlane(rt[0]);
    const int io2 = __builtin_amdgcn_readfirstlane(rt[1]);
    int m[4], srcs[8];
#pragma unroll
    for (int k = 0; k < 4; ++k)
        m[k] = __builtin_amdgcn_readfirstlane(rt[2 + k]);
#pragma unroll
    for (int s = 0; s < 8; ++s)
        srcs[s] = __builtin_amdgcn_readfirstlane(rt[14 + s]);

    // ---- stage: stream 256 rows (64KB) fully coalesced; deposit routed ----
    const size_t xbase = (size_t)blockIdx.x * (256 * 64) + t;
    const int rsub = t >> 6;               // row-within-quad for this thread
#pragma unroll
    for (int jb = 0; jb < 4; ++jb) {
        float v[16];
#pragma unroll
        for (int ji = 0; ji < 16; ++ji)
            v[ji] = x[xbase + (size_t)(jb * 16 + ji) * 256];
#pragma unroll
        for (int ji = 0; ji < 16; ++ji) {
            const int rloc = (jb * 16 + ji) * 4 + rsub;
            if (slot >= 0) buf[rloc * 9 + slot] = v[ji];
        }
    }
    __syncthreads();

    // ---- gather this row's 8 routed features (conflict-free ds_reads) ----
    float f[8];
#pragma unroll
    for (int s = 0; s < 8; ++s) f[s] = buf[t * 9 + srcs[s]];

    // ---- layer 0: 4 active modules, f32, scalar weights ----
    float y[4];
#pragma unroll
    for (int k = 0; k < 4; ++k) {
        const float* w1 = W1_0 + m[k] * 24;
        const float* bb = b1_0 + m[k] * 12;
        const float* w2 = W2_0 + m[k] * 12;
        const float va = f[2 * k], vb = f[2 * k + 1];
        float acc = b2_0[m[k]];
#pragma unroll
        for (int j = 0; j < 12; ++j) {
            float h = fmaf(va, w1[j], fmaf(vb, w1[12 + j], bb[j]));
            acc = fmaf(fmaxf(h, 0.0f), w2[j], acc);
        }
        y[k] = acc;
    }

    // ---- layer 1: io1 consumes (y[0],y[1]); io2 consumes (y[2],y[3]) ----
    float z[2];
    const int mo[2] = {io1, io2};
#pragma unroll
    for (int k = 0; k < 2; ++k) {
        const float* w1 = W1_1 + mo[k] * 24;
        const float* bb = b1_1 + mo[k] * 12;
        const float* w2 = W2_1 + mo[k] * 12;
        const float g1 = k ? y[2] : y[0];
        const float g2 = k ? y[3] : y[1];
        float acc = b2_1[mo[k]];
#pragma unroll
        for (int j = 0; j < 12; ++j) {
            float h = fmaf(g1, w1[j], fmaf(g2, w1[12 + j], bb[j]));
            acc = fmaf(fmaxf(h, 0.0f), w2[j], acc);
        }
        z[k] = acc;
    }

    float2 res;
    res.x = 1.0f / (1.0f + __expf(-z[0]));
    res.y = 1.0f / (1.0f + __expf(-z[1]));
    reinterpret_cast<float2*>(out)[(size_t)blockIdx.x * 256 + t] = res;
}

extern "C" void kernel_launch(void* const* d_in, const int* in_sizes, int n_in,
                              void* d_out, int out_size, void* d_ws, size_t ws_size,
                              hipStream_t stream) {
    const float* x       = (const float*)d_in[0];
    // d_in[1] = task_id; NUM_TASKS == 1 so always 0.
    const float* emb0    = (const float*)d_in[2];
    const float* emb1    = (const float*)d_in[3];
    const float* emb_out = (const float*)d_in[4];
    const float* W1_0    = (const float*)d_in[5];
    const float* b1_0    = (const float*)d_in[6];
    const float* W2_0    = (const float*)d_in[7];
    const float* b2_0    = (const float*)d_in[8];
    const float* W1_1    = (const float*)d_in[9];
    const float* b1_1    = (const float*)d_in[10];
    const float* W2_1    = (const float*)d_in[11];
    const float* b2_1    = (const float*)d_in[12];

    moe_sparse<<<NROWS / TPB, TPB, 0, stream>>>(
        x, emb0, emb1, emb_out,
        W1_0, b1_0, W2_0, b2_0, W1_1, b1_1, W2_1, b2_1,
        (float*)d_out);
}